// Round 1
// baseline (1722.865 us; speedup 1.0000x reference)
//
#include <hip/hip_runtime.h>

#define NB 8
#define NPTS 100000
#define C_DIM 32
#define RESO 64
#define R3 (RESO * RESO * RESO)

// One thread per (batch, point): compute voxel bin, atomically accumulate
// count and all 32 channel features.
__global__ void __launch_bounds__(256)
scatter_kernel(const float* __restrict__ points,
               const float* __restrict__ feature,
               float* __restrict__ sums,   // [B, C, R3] == d_out
               float* __restrict__ cnt) {  // [B, R3]
    int t = blockIdx.x * blockDim.x + threadIdx.x;
    if (t >= NB * NPTS) return;
    int b = t / NPTS;
    int n = t - b * NPTS;

    const float* p = points + (size_t)t * 3;
    float x = p[0], y = p[1], z = p[2];

    // Must match numpy f32 ops bitwise: p / 2.2f + 0.5f ; clip ; * 64 ; floor
    const float LIM = 1.0f - 1e-6f;
    float cx = fminf(fmaxf(x / 2.2f + 0.5f, 0.0f), LIM);
    float cy = fminf(fmaxf(y / 2.2f + 0.5f, 0.0f), LIM);
    float cz = fminf(fmaxf(z / 2.2f + 0.5f, 0.0f), LIM);
    int i = (int)floorf(cx * 64.0f);
    int j = (int)floorf(cy * 64.0f);
    int k = (int)floorf(cz * 64.0f);
    int idx = i + RESO * (j + RESO * k);

    atomicAdd(cnt + (size_t)b * R3 + idx, 1.0f);

    size_t obase = ((size_t)b * C_DIM) * R3 + idx;
    size_t fbase = ((size_t)b * C_DIM) * NPTS + n;
#pragma unroll
    for (int c = 0; c < C_DIM; ++c) {
        atomicAdd(sums + obase + (size_t)c * R3, feature[fbase + (size_t)c * NPTS]);
    }
}

// One thread per (batch, voxel): divide all 32 channels by max(count, 1).
__global__ void __launch_bounds__(256)
normalize_kernel(float* __restrict__ out, const float* __restrict__ cnt) {
    int t = blockIdx.x * blockDim.x + threadIdx.x;
    if (t >= NB * R3) return;
    int b = t >> 18;            // R3 = 2^18
    int v = t & (R3 - 1);
    float d = fmaxf(cnt[t], 1.0f);
    size_t base = ((size_t)b * C_DIM) * R3 + v;
#pragma unroll
    for (int c = 0; c < C_DIM; ++c) {
        out[base + (size_t)c * R3] = out[base + (size_t)c * R3] / d;
    }
}

extern "C" void kernel_launch(void* const* d_in, const int* in_sizes, int n_in,
                              void* d_out, int out_size, void* d_ws, size_t ws_size,
                              hipStream_t stream) {
    const float* points  = (const float*)d_in[0];   // [B, N, 3]
    const float* feature = (const float*)d_in[1];   // [B, C, N]
    float* out = (float*)d_out;                     // [B, C, R3]
    float* cnt = (float*)d_ws;                      // [B, R3]

    hipMemsetAsync(d_out, 0, (size_t)out_size * sizeof(float), stream);
    hipMemsetAsync(d_ws, 0, (size_t)NB * R3 * sizeof(float), stream);

    int total = NB * NPTS;
    int blk = 256;
    scatter_kernel<<<(total + blk - 1) / blk, blk, 0, stream>>>(points, feature, out, cnt);

    int total2 = NB * R3;
    normalize_kernel<<<(total2 + blk - 1) / blk, blk, 0, stream>>>(out, cnt);
}

// Round 2
// 773.395 us; speedup vs baseline: 2.2277x; 2.2277x over previous
//
#include <hip/hip_runtime.h>

#define NB 8
#define NPTS 100000
#define C_DIM 32
#define RESO 64
#define R3 (RESO * RESO * RESO)     // 262144 = 2^18
#define CHUNK 1024                  // bins per scan chunk
#define NCHUNK (R3 / CHUNK)         // 256 chunks per batch
#define TOTCHUNK (NB * NCHUNK)      // 2048 chunks total

// Workspace layout (byte offsets, all 16B-aligned)
#define OFF_IDX   0                         // [B*N] int   (3.2 MB)
#define OFF_HIST  (NB * NPTS * 4)           // [B*R3] int  (8 MB)   3,200,000
#define OFF_LSCAN (OFF_HIST + NB * R3 * 4)  // [B*R3] int  (8 MB)
#define OFF_CTOT  (OFF_LSCAN + NB * R3 * 4) // [2048] int
#define OFF_COFF  (OFF_CTOT + TOTCHUNK * 4) // [2048] int
#define OFF_PERM  (OFF_COFF + TOTCHUNK * 4) // [B*N] int   (3.2 MB)

// ---------------- K1: bin index per point + histogram ----------------
__global__ void __launch_bounds__(256)
k1_index_hist(const float* __restrict__ points, int* __restrict__ idxArr,
              int* __restrict__ hist) {
    int t = blockIdx.x * 256 + threadIdx.x;
    if (t >= NB * NPTS) return;
    const float* p = points + (size_t)t * 3;
    float x = p[0], y = p[1], z = p[2];

    // bit-identical to numpy ref: p / 2.2f + 0.5f ; clip[0, 1-1e-6] ; *64 ; floor
    const float LIM = 1.0f - 1e-6f;
    float cx = fminf(fmaxf(x / 2.2f + 0.5f, 0.0f), LIM);
    float cy = fminf(fmaxf(y / 2.2f + 0.5f, 0.0f), LIM);
    float cz = fminf(fmaxf(z / 2.2f + 0.5f, 0.0f), LIM);
    int i = (int)floorf(cx * 64.0f);
    int j = (int)floorf(cy * 64.0f);
    int k = (int)floorf(cz * 64.0f);
    int idx = i + RESO * (j + RESO * k);

    idxArr[t] = idx;
    int b = t / NPTS;
    atomicAdd(hist + b * R3 + idx, 1);
}

// ---------------- S1: per-chunk (1024 bins) exclusive scan ----------------
__global__ void __launch_bounds__(256)
s1_local_scan(const int* __restrict__ hist, int* __restrict__ lscan,
              int* __restrict__ ctot) {
    int chunk = blockIdx.x;            // 0..2047 (never straddles a batch)
    int tid = threadIdx.x;
    int4 v = *reinterpret_cast<const int4*>(hist + chunk * CHUNK + tid * 4);
    int tot = v.x + v.y + v.z + v.w;

    __shared__ int sm[256];
    sm[tid] = tot;
    __syncthreads();
    for (int off = 1; off < 256; off <<= 1) {
        int x = (tid >= off) ? sm[tid - off] : 0;
        __syncthreads();
        sm[tid] += x;
        __syncthreads();
    }
    int base = sm[tid] - tot;          // exclusive prefix of this thread's 4
    int4 o;
    o.x = base;
    o.y = base + v.x;
    o.z = base + v.x + v.y;
    o.w = base + v.x + v.y + v.z;
    *reinterpret_cast<int4*>(lscan + chunk * CHUNK + tid * 4) = o;
    if (tid == 255) ctot[chunk] = sm[255];
}

// ---------------- S2: per-batch scan of 256 chunk totals ----------------
__global__ void __launch_bounds__(256)
s2_chunk_scan(const int* __restrict__ ctot, int* __restrict__ coff) {
    int b = blockIdx.x;
    int tid = threadIdx.x;
    int v = ctot[b * NCHUNK + tid];
    __shared__ int sm[256];
    sm[tid] = v;
    __syncthreads();
    for (int off = 1; off < 256; off <<= 1) {
        int x = (tid >= off) ? sm[tid - off] : 0;
        __syncthreads();
        sm[tid] += x;
        __syncthreads();
    }
    coff[b * NCHUNK + tid] = sm[tid] - v;   // exclusive
}

// ---------------- K3: build permutation (counting-sort placement) ----------------
__global__ void __launch_bounds__(256)
k3_permute(const int* __restrict__ idxArr, int* __restrict__ lscan,
           const int* __restrict__ coff, int* __restrict__ perm) {
    int t = blockIdx.x * 256 + threadIdx.x;
    if (t >= NB * NPTS) return;
    int b = t / NPTS;
    int n = t - b * NPTS;
    int idx = idxArr[t];
    int g = b * R3 + idx;
    // lscan becomes "local end" after all atomics complete
    int pos = coff[g >> 10] + atomicAdd(lscan + g, 1);
    perm[b * NPTS + pos] = n;
}

// ---------------- K5: per-voxel gather + mean + store (fused normalize) ----------------
__global__ void __launch_bounds__(256)
k5_reduce(const int* __restrict__ lscan, const int* __restrict__ coff,
          const int* __restrict__ hist, const int* __restrict__ perm,
          const float* __restrict__ feature, float* __restrict__ out) {
    int t = blockIdx.x * 256 + threadIdx.x;   // 0 .. NB*R3-1
    int b = t >> 18;
    int v = t & (R3 - 1);

    int end = coff[t >> 10] + lscan[t];       // lscan holds local_start+cnt now
    int cnt = hist[t];
    int start = end - cnt;

    float acc[C_DIM];
#pragma unroll
    for (int c = 0; c < C_DIM; ++c) acc[c] = 0.0f;

    const float* fb = feature + (size_t)b * C_DIM * NPTS;
    const int* pm = perm + b * NPTS;
    for (int p = start; p < end; ++p) {
        int n = pm[p];
#pragma unroll
        for (int c = 0; c < C_DIM; ++c) acc[c] += fb[(size_t)c * NPTS + n];
    }

    float d = (float)max(cnt, 1);
    size_t obase = ((size_t)b * C_DIM) * R3 + v;
#pragma unroll
    for (int c = 0; c < C_DIM; ++c) out[obase + (size_t)c * R3] = acc[c] / d;
}

extern "C" void kernel_launch(void* const* d_in, const int* in_sizes, int n_in,
                              void* d_out, int out_size, void* d_ws, size_t ws_size,
                              hipStream_t stream) {
    const float* points  = (const float*)d_in[0];   // [B, N, 3]
    const float* feature = (const float*)d_in[1];   // [B, C, N]
    float* out = (float*)d_out;                     // [B, C, R3]

    char* ws = (char*)d_ws;
    int* idxArr = (int*)(ws + OFF_IDX);
    int* hist   = (int*)(ws + OFF_HIST);
    int* lscan  = (int*)(ws + OFF_LSCAN);
    int* ctot   = (int*)(ws + OFF_CTOT);
    int* coff   = (int*)(ws + OFF_COFF);
    int* perm   = (int*)(ws + OFF_PERM);

    // only hist needs zeroing; everything else is fully written before read
    hipMemsetAsync(hist, 0, (size_t)NB * R3 * sizeof(int), stream);

    int totalPts = NB * NPTS;
    k1_index_hist<<<(totalPts + 255) / 256, 256, 0, stream>>>(points, idxArr, hist);
    s1_local_scan<<<TOTCHUNK, 256, 0, stream>>>(hist, lscan, ctot);
    s2_chunk_scan<<<NB, 256, 0, stream>>>(ctot, coff);
    k3_permute<<<(totalPts + 255) / 256, 256, 0, stream>>>(idxArr, lscan, coff, perm);
    k5_reduce<<<(NB * R3) / 256, 256, 0, stream>>>(lscan, coff, hist, perm, feature, out);
}

// Round 3
// 524.750 us; speedup vs baseline: 3.2832x; 1.4738x over previous
//
#include <hip/hip_runtime.h>

#define NB 8
#define NPTS 100000
#define C_DIM 32
#define RESO 64
#define R3 (RESO * RESO * RESO)     // 262144 = 2^18
#define CHUNK 1024                  // bins per scan chunk
#define NCHUNK (R3 / CHUNK)         // 256 chunks per batch
#define TOTCHUNK (NB * NCHUNK)      // 2048 chunks total
#define NPTS_TOT (NB * NPTS)        // 800000
#define NTILE ((NPTS + 255) / 256)  // 391 tiles per batch

// Workspace layout (byte offsets, 16B-aligned)
#define OFF_IDX   0u                              // [800000] int
#define OFF_HIST  3200000u                        // [B*R3] int (8 MB)
#define OFF_LSCAN (OFF_HIST + 8388608u)           // [B*R3] int (8 MB)
#define OFF_CTOT  (OFF_LSCAN + 8388608u)          // [2048] int
#define OFF_COFF  (OFF_CTOT + 8192u)              // [2048] int
#define OFF_PERM  (OFF_COFF + 8192u)              // path B: [800000] int
#define OFF_FPERM (OFF_COFF + 8192u)              // path A: [800000][32] float (102.4 MB)
#define WS_NEED_A (OFF_FPERM + (size_t)NPTS_TOT * C_DIM * 4)
#define WS_NEED_B (OFF_PERM + (size_t)NPTS_TOT * 4)

// ---------------- K1: bin index per point + histogram ----------------
__global__ void __launch_bounds__(256)
k1_index_hist(const float* __restrict__ points, int* __restrict__ idxArr,
              int* __restrict__ hist) {
    int t = blockIdx.x * 256 + threadIdx.x;
    if (t >= NPTS_TOT) return;
    const float* p = points + (size_t)t * 3;
    // bit-identical to numpy ref: p / 2.2f + 0.5f ; clip[0, 1-1e-6] ; *64 ; floor
    const float LIM = 1.0f - 1e-6f;
    float cx = fminf(fmaxf(p[0] / 2.2f + 0.5f, 0.0f), LIM);
    float cy = fminf(fmaxf(p[1] / 2.2f + 0.5f, 0.0f), LIM);
    float cz = fminf(fmaxf(p[2] / 2.2f + 0.5f, 0.0f), LIM);
    int i = (int)floorf(cx * 64.0f);
    int j = (int)floorf(cy * 64.0f);
    int k = (int)floorf(cz * 64.0f);
    int idx = i + RESO * (j + RESO * k);
    idxArr[t] = idx;
    int b = t / NPTS;
    atomicAdd(hist + b * R3 + idx, 1);
}

// ---------------- S1: per-chunk (1024 bins) exclusive scan ----------------
__global__ void __launch_bounds__(256)
s1_local_scan(const int* __restrict__ hist, int* __restrict__ lscan,
              int* __restrict__ ctot) {
    int chunk = blockIdx.x;            // 0..2047
    int tid = threadIdx.x;
    int4 v = *reinterpret_cast<const int4*>(hist + chunk * CHUNK + tid * 4);
    int tot = v.x + v.y + v.z + v.w;
    __shared__ int sm[256];
    sm[tid] = tot;
    __syncthreads();
    for (int off = 1; off < 256; off <<= 1) {
        int x = (tid >= off) ? sm[tid - off] : 0;
        __syncthreads();
        sm[tid] += x;
        __syncthreads();
    }
    int base = sm[tid] - tot;
    int4 o;
    o.x = base;
    o.y = base + v.x;
    o.z = base + v.x + v.y;
    o.w = base + v.x + v.y + v.z;
    *reinterpret_cast<int4*>(lscan + chunk * CHUNK + tid * 4) = o;
    if (tid == 255) ctot[chunk] = sm[255];
}

// ---------------- S2: single-block GLOBAL scan of 2048 chunk totals ----------------
__global__ void __launch_bounds__(256)
s2_chunk_scan(const int* __restrict__ ctot, int* __restrict__ coff) {
    int tid = threadIdx.x;
    int v[8];
#pragma unroll
    for (int j = 0; j < 8; ++j) v[j] = ctot[tid * 8 + j];
    int run = 0;
#pragma unroll
    for (int j = 0; j < 8; ++j) { int x = v[j]; v[j] = run; run += x; }
    __shared__ int sm[256];
    sm[tid] = run;
    __syncthreads();
    for (int off = 1; off < 256; off <<= 1) {
        int x = (tid >= off) ? sm[tid - off] : 0;
        __syncthreads();
        sm[tid] += x;
        __syncthreads();
    }
    int base = sm[tid] - run;
#pragma unroll
    for (int j = 0; j < 8; ++j) coff[tid * 8 + j] = base + v[j];
}

// ---------------- T (path A): transpose feature tile + scatter rows to sorted order ----
__global__ void __launch_bounds__(256)
t_permute(const float* __restrict__ feature, const int* __restrict__ idxArr,
          int* __restrict__ lscan, const int* __restrict__ coff,
          float* __restrict__ fperm) {
    int b = blockIdx.y;
    int n0 = blockIdx.x * 256;
    int tid = threadIdx.x;
    int n = n0 + tid;
    bool valid = n < NPTS;

    __shared__ float sm[32][257];
    __shared__ int sm_pos[256];

    // phase 1: coalesced load of 32x256 tile
    const float* fb = feature + (size_t)b * C_DIM * NPTS;
#pragma unroll
    for (int c = 0; c < C_DIM; ++c)
        sm[c][tid] = valid ? fb[(size_t)c * NPTS + n] : 0.0f;

    // phase 1.5: sorted position per point (consumes the scan cursor)
    if (valid) {
        int idx = idxArr[b * NPTS + n];
        int g = b * R3 + idx;
        sm_pos[tid] = coff[g >> 10] + atomicAdd(lscan + g, 1);
    }
    __syncthreads();

    // phase 2: 8 lanes per point write one contiguous 128B row
    int cg = tid & 7;          // float4 index within row
    int qb = tid >> 3;         // 0..31
#pragma unroll
    for (int it = 0; it < 8; ++it) {
        int q = it * 32 + qb;
        if (n0 + q < NPTS) {
            float4 r;
            r.x = sm[cg * 4 + 0][q];
            r.y = sm[cg * 4 + 1][q];
            r.z = sm[cg * 4 + 2][q];
            r.w = sm[cg * 4 + 3][q];
            *reinterpret_cast<float4*>(fperm + (size_t)sm_pos[q] * C_DIM + cg * 4) = r;
        }
    }
}

// ---------------- K5 (path A): per-voxel streaming reduce + mean ----------------
__global__ void __launch_bounds__(256)
k5_reduce_a(const int* __restrict__ lscan, const int* __restrict__ coff,
            const int* __restrict__ hist, const float* __restrict__ fperm,
            float* __restrict__ out) {
    int t = blockIdx.x * 256 + threadIdx.x;   // global bin id
    int b = t >> 18;
    int v = t & (R3 - 1);
    int end = coff[t >> 10] + lscan[t];       // lscan = local_start + cnt now
    int cnt = hist[t];
    int start = end - cnt;

    float acc[C_DIM];
#pragma unroll
    for (int c = 0; c < C_DIM; ++c) acc[c] = 0.0f;

    for (int p = start; p < end; ++p) {
        const float4* row = reinterpret_cast<const float4*>(fperm + (size_t)p * C_DIM);
#pragma unroll
        for (int q = 0; q < 8; ++q) {
            float4 r = row[q];
            acc[q * 4 + 0] += r.x;
            acc[q * 4 + 1] += r.y;
            acc[q * 4 + 2] += r.z;
            acc[q * 4 + 3] += r.w;
        }
    }
    float d = (float)max(cnt, 1);
    size_t obase = ((size_t)b * C_DIM) * R3 + v;
#pragma unroll
    for (int c = 0; c < C_DIM; ++c) out[obase + (size_t)c * R3] = acc[c] / d;
}

// ---------------- Path B fallback (small workspace): round-2 pipeline ----------------
__global__ void __launch_bounds__(256)
k3_permute(const int* __restrict__ idxArr, int* __restrict__ lscan,
           const int* __restrict__ coff, int* __restrict__ perm) {
    int t = blockIdx.x * 256 + threadIdx.x;
    if (t >= NPTS_TOT) return;
    int b = t / NPTS;
    int g = b * R3 + idxArr[t];
    int pos = coff[g >> 10] + atomicAdd(lscan + g, 1);
    perm[pos] = t;
}

__global__ void __launch_bounds__(256)
k5_reduce_b(const int* __restrict__ lscan, const int* __restrict__ coff,
            const int* __restrict__ hist, const int* __restrict__ perm,
            const float* __restrict__ feature, float* __restrict__ out) {
    int t = blockIdx.x * 256 + threadIdx.x;
    int b = t >> 18;
    int v = t & (R3 - 1);
    int end = coff[t >> 10] + lscan[t];
    int cnt = hist[t];
    int start = end - cnt;

    float acc[C_DIM];
#pragma unroll
    for (int c = 0; c < C_DIM; ++c) acc[c] = 0.0f;
    const float* fb = feature + (size_t)b * C_DIM * NPTS;
    for (int p = start; p < end; ++p) {
        int n = perm[p] - b * NPTS;
#pragma unroll
        for (int c = 0; c < C_DIM; ++c) acc[c] += fb[(size_t)c * NPTS + n];
    }
    float d = (float)max(cnt, 1);
    size_t obase = ((size_t)b * C_DIM) * R3 + v;
#pragma unroll
    for (int c = 0; c < C_DIM; ++c) out[obase + (size_t)c * R3] = acc[c] / d;
}

extern "C" void kernel_launch(void* const* d_in, const int* in_sizes, int n_in,
                              void* d_out, int out_size, void* d_ws, size_t ws_size,
                              hipStream_t stream) {
    const float* points  = (const float*)d_in[0];   // [B, N, 3]
    const float* feature = (const float*)d_in[1];   // [B, C, N]
    float* out = (float*)d_out;                     // [B, C, R3]

    char* ws = (char*)d_ws;
    int* idxArr = (int*)(ws + OFF_IDX);
    int* hist   = (int*)(ws + OFF_HIST);
    int* lscan  = (int*)(ws + OFF_LSCAN);
    int* ctot   = (int*)(ws + OFF_CTOT);
    int* coff   = (int*)(ws + OFF_COFF);

    hipMemsetAsync(hist, 0, (size_t)NB * R3 * sizeof(int), stream);

    k1_index_hist<<<(NPTS_TOT + 255) / 256, 256, 0, stream>>>(points, idxArr, hist);
    s1_local_scan<<<TOTCHUNK, 256, 0, stream>>>(hist, lscan, ctot);
    s2_chunk_scan<<<1, 256, 0, stream>>>(ctot, coff);

    if (ws_size >= WS_NEED_A) {
        float* fperm = (float*)(ws + OFF_FPERM);
        dim3 tgrid(NTILE, NB);
        t_permute<<<tgrid, 256, 0, stream>>>(feature, idxArr, lscan, coff, fperm);
        k5_reduce_a<<<(NB * R3) / 256, 256, 0, stream>>>(lscan, coff, hist, fperm, out);
    } else {
        int* perm = (int*)(ws + OFF_PERM);
        k3_permute<<<(NPTS_TOT + 255) / 256, 256, 0, stream>>>(idxArr, lscan, coff, perm);
        k5_reduce_b<<<(NB * R3) / 256, 256, 0, stream>>>(lscan, coff, hist, perm, feature, out);
    }
}

// Round 4
// 443.477 us; speedup vs baseline: 3.8849x; 1.1833x over previous
//
#include <hip/hip_runtime.h>

#define NB 8
#define NPTS 100000
#define C_DIM 32
#define RESO 64
#define R3 (RESO * RESO * RESO)     // 262144 = 2^18
#define CHUNK 1024                  // bins per scan chunk
#define NCHUNK (R3 / CHUNK)         // 256 chunks per batch
#define TOTCHUNK (NB * NCHUNK)      // 2048 chunks total
#define NPTS_TOT (NB * NPTS)        // 800000
#define NTILE ((NPTS + 255) / 256)  // 391 tiles per batch

// Workspace layout (byte offsets, 16B-aligned)
#define OFF_IDX   0u                              // [800000] int
#define OFF_HIST  3200000u                        // [B*R3] int (8 MB)
#define OFF_LSCAN (OFF_HIST + 8388608u)           // [B*R3] int (8 MB)
#define OFF_CTOT  (OFF_LSCAN + 8388608u)          // [2048] int
#define OFF_COFF  (OFF_CTOT + 8192u)              // [2048] int
#define OFF_PERM  (OFF_COFF + 8192u)              // path B: [800000] int
#define OFF_FPERM (OFF_COFF + 8192u)              // path A: [800000][32] fp16 (51.2 MB)
#define WS_NEED_A (OFF_FPERM + (size_t)NPTS_TOT * C_DIM * 2)
#define WS_NEED_B (OFF_PERM + (size_t)NPTS_TOT * 4)

union H8 { uint4 v; _Float16 h[8]; };

// ---------------- K1: bin index per point + histogram ----------------
__global__ void __launch_bounds__(256)
k1_index_hist(const float* __restrict__ points, int* __restrict__ idxArr,
              int* __restrict__ hist) {
    int t = blockIdx.x * 256 + threadIdx.x;
    if (t >= NPTS_TOT) return;
    const float* p = points + (size_t)t * 3;
    float x = __builtin_nontemporal_load(p + 0);
    float y = __builtin_nontemporal_load(p + 1);
    float z = __builtin_nontemporal_load(p + 2);
    // bit-identical to numpy ref: p / 2.2f + 0.5f ; clip[0, 1-1e-6] ; *64 ; floor
    const float LIM = 1.0f - 1e-6f;
    float cx = fminf(fmaxf(x / 2.2f + 0.5f, 0.0f), LIM);
    float cy = fminf(fmaxf(y / 2.2f + 0.5f, 0.0f), LIM);
    float cz = fminf(fmaxf(z / 2.2f + 0.5f, 0.0f), LIM);
    int i = (int)floorf(cx * 64.0f);
    int j = (int)floorf(cy * 64.0f);
    int k = (int)floorf(cz * 64.0f);
    int idx = i + RESO * (j + RESO * k);
    idxArr[t] = idx;
    int b = t / NPTS;
    atomicAdd(hist + b * R3 + idx, 1);
}

// ---------------- S1: per-chunk (1024 bins) exclusive scan ----------------
__global__ void __launch_bounds__(256)
s1_local_scan(const int* __restrict__ hist, int* __restrict__ lscan,
              int* __restrict__ ctot) {
    int chunk = blockIdx.x;            // 0..2047
    int tid = threadIdx.x;
    int4 v = *reinterpret_cast<const int4*>(hist + chunk * CHUNK + tid * 4);
    int tot = v.x + v.y + v.z + v.w;
    __shared__ int sm[256];
    sm[tid] = tot;
    __syncthreads();
    for (int off = 1; off < 256; off <<= 1) {
        int x = (tid >= off) ? sm[tid - off] : 0;
        __syncthreads();
        sm[tid] += x;
        __syncthreads();
    }
    int base = sm[tid] - tot;
    int4 o;
    o.x = base;
    o.y = base + v.x;
    o.z = base + v.x + v.y;
    o.w = base + v.x + v.y + v.z;
    *reinterpret_cast<int4*>(lscan + chunk * CHUNK + tid * 4) = o;
    if (tid == 255) ctot[chunk] = sm[255];
}

// ---------------- S2: single-block GLOBAL scan of 2048 chunk totals ----------------
__global__ void __launch_bounds__(256)
s2_chunk_scan(const int* __restrict__ ctot, int* __restrict__ coff) {
    int tid = threadIdx.x;
    int v[8];
#pragma unroll
    for (int j = 0; j < 8; ++j) v[j] = ctot[tid * 8 + j];
    int run = 0;
#pragma unroll
    for (int j = 0; j < 8; ++j) { int x = v[j]; v[j] = run; run += x; }
    __shared__ int sm[256];
    sm[tid] = run;
    __syncthreads();
    for (int off = 1; off < 256; off <<= 1) {
        int x = (tid >= off) ? sm[tid - off] : 0;
        __syncthreads();
        sm[tid] += x;
        __syncthreads();
    }
    int base = sm[tid] - run;
#pragma unroll
    for (int j = 0; j < 8; ++j) coff[tid * 8 + j] = base + v[j];
}

// ---- T (path A): transpose feature tile, convert fp16, scatter 64B rows to sorted order
__global__ void __launch_bounds__(256)
t_permute(const float* __restrict__ feature, const int* __restrict__ idxArr,
          int* __restrict__ lscan, const int* __restrict__ coff,
          ushort* __restrict__ fperm) {
    int b = blockIdx.y;
    int n0 = blockIdx.x * 256;
    int tid = threadIdx.x;
    int n = n0 + tid;
    bool valid = n < NPTS;

    __shared__ float sm[32][257];
    __shared__ int sm_pos[256];

    // phase 1: coalesced (nontemporal) load of 32x256 tile
    const float* fb = feature + (size_t)b * C_DIM * NPTS;
#pragma unroll
    for (int c = 0; c < C_DIM; ++c)
        sm[c][tid] = valid ? __builtin_nontemporal_load(fb + (size_t)c * NPTS + n) : 0.0f;

    // phase 1.5: sorted position per point (consumes the scan cursor)
    if (valid) {
        int idx = idxArr[b * NPTS + n];
        int g = b * R3 + idx;
        sm_pos[tid] = coff[g >> 10] + atomicAdd(lscan + g, 1);
    }
    __syncthreads();

    // phase 2: 4 lanes per point; each converts 8 channels to fp16, writes 16B
    int cg = tid & 3;          // which 8-channel group
    int qb = tid >> 2;         // 0..63
#pragma unroll
    for (int it = 0; it < 4; ++it) {
        int q = it * 64 + qb;
        if (n0 + q < NPTS) {
            H8 r;
#pragma unroll
            for (int j = 0; j < 8; ++j)
                r.h[j] = (_Float16)sm[cg * 8 + j][q];
            *reinterpret_cast<uint4*>(fperm + (size_t)sm_pos[q] * C_DIM + cg * 8) = r.v;
        }
    }
}

// ---------------- K5 (path A): per-voxel streaming reduce + mean ----------------
__global__ void __launch_bounds__(256)
k5_reduce_a(const int* __restrict__ lscan, const int* __restrict__ coff,
            const int* __restrict__ hist, const ushort* __restrict__ fperm,
            float* __restrict__ out) {
    int t = blockIdx.x * 256 + threadIdx.x;   // global bin id
    int b = t >> 18;
    int v = t & (R3 - 1);
    int end = coff[t >> 10] + lscan[t];       // lscan = local_start + cnt now
    int cnt = hist[t];
    int start = end - cnt;

    float acc[C_DIM];
#pragma unroll
    for (int c = 0; c < C_DIM; ++c) acc[c] = 0.0f;

    for (int p = start; p < end; ++p) {
        const uint4* row = reinterpret_cast<const uint4*>(fperm + (size_t)p * C_DIM);
#pragma unroll
        for (int g = 0; g < 4; ++g) {
            H8 r;
            r.v = row[g];
#pragma unroll
            for (int j = 0; j < 8; ++j) acc[g * 8 + j] += (float)r.h[j];
        }
    }
    float d = (float)max(cnt, 1);
    size_t obase = ((size_t)b * C_DIM) * R3 + v;
#pragma unroll
    for (int c = 0; c < C_DIM; ++c)
        __builtin_nontemporal_store(acc[c] / d, out + obase + (size_t)c * R3);
}

// ---------------- Path B fallback (small workspace): round-2 pipeline ----------------
__global__ void __launch_bounds__(256)
k3_permute(const int* __restrict__ idxArr, int* __restrict__ lscan,
           const int* __restrict__ coff, int* __restrict__ perm) {
    int t = blockIdx.x * 256 + threadIdx.x;
    if (t >= NPTS_TOT) return;
    int b = t / NPTS;
    int g = b * R3 + idxArr[t];
    int pos = coff[g >> 10] + atomicAdd(lscan + g, 1);
    perm[pos] = t;
}

__global__ void __launch_bounds__(256)
k5_reduce_b(const int* __restrict__ lscan, const int* __restrict__ coff,
            const int* __restrict__ hist, const int* __restrict__ perm,
            const float* __restrict__ feature, float* __restrict__ out) {
    int t = blockIdx.x * 256 + threadIdx.x;
    int b = t >> 18;
    int v = t & (R3 - 1);
    int end = coff[t >> 10] + lscan[t];
    int cnt = hist[t];
    int start = end - cnt;

    float acc[C_DIM];
#pragma unroll
    for (int c = 0; c < C_DIM; ++c) acc[c] = 0.0f;
    const float* fb = feature + (size_t)b * C_DIM * NPTS;
    for (int p = start; p < end; ++p) {
        int n = perm[p] - b * NPTS;
#pragma unroll
        for (int c = 0; c < C_DIM; ++c) acc[c] += fb[(size_t)c * NPTS + n];
    }
    float d = (float)max(cnt, 1);
    size_t obase = ((size_t)b * C_DIM) * R3 + v;
#pragma unroll
    for (int c = 0; c < C_DIM; ++c) out[obase + (size_t)c * R3] = acc[c] / d;
}

extern "C" void kernel_launch(void* const* d_in, const int* in_sizes, int n_in,
                              void* d_out, int out_size, void* d_ws, size_t ws_size,
                              hipStream_t stream) {
    const float* points  = (const float*)d_in[0];   // [B, N, 3]
    const float* feature = (const float*)d_in[1];   // [B, C, N]
    float* out = (float*)d_out;                     // [B, C, R3]

    char* ws = (char*)d_ws;
    int* idxArr = (int*)(ws + OFF_IDX);
    int* hist   = (int*)(ws + OFF_HIST);
    int* lscan  = (int*)(ws + OFF_LSCAN);
    int* ctot   = (int*)(ws + OFF_CTOT);
    int* coff   = (int*)(ws + OFF_COFF);

    hipMemsetAsync(hist, 0, (size_t)NB * R3 * sizeof(int), stream);

    k1_index_hist<<<(NPTS_TOT + 255) / 256, 256, 0, stream>>>(points, idxArr, hist);
    s1_local_scan<<<TOTCHUNK, 256, 0, stream>>>(hist, lscan, ctot);
    s2_chunk_scan<<<1, 256, 0, stream>>>(ctot, coff);

    if (ws_size >= WS_NEED_A) {
        ushort* fperm = (ushort*)(ws + OFF_FPERM);
        dim3 tgrid(NTILE, NB);
        t_permute<<<tgrid, 256, 0, stream>>>(feature, idxArr, lscan, coff, fperm);
        k5_reduce_a<<<(NB * R3) / 256, 256, 0, stream>>>(lscan, coff, hist, fperm, out);
    } else {
        int* perm = (int*)(ws + OFF_PERM);
        k3_permute<<<(NPTS_TOT + 255) / 256, 256, 0, stream>>>(idxArr, lscan, coff, perm);
        k5_reduce_b<<<(NB * R3) / 256, 256, 0, stream>>>(lscan, coff, hist, perm, feature, out);
    }
}